// Round 5
// baseline (3118.227 us; speedup 1.0000x reference)
//
#include <hip/hip_runtime.h>
#include <math.h>

#define B_SZ 8
#define S_LEN 1025
#define DIM 1024
#define NH 16
#define HD 64
#define QKV_DIM 3072
#define M_ROWS (B_SZ * S_LEN)   // 8200

typedef __attribute__((ext_vector_type(8))) short bf16x8;
typedef __attribute__((ext_vector_type(4))) float f32x4;

// ---------------------------------------------------------------------------
// fp32 -> bf16 (RNE) split helpers: x ~= hi + lo, |x-hi-lo| <= ~2^-18 |x|.
// ---------------------------------------------------------------------------
__device__ __forceinline__ unsigned short f2bf(float x) {
  unsigned u = __float_as_uint(x);
  unsigned r = u + 0x7FFFu + ((u >> 16) & 1u);
  return (unsigned short)(r >> 16);
}
__device__ __forceinline__ float bf2f(unsigned short h) {
  return __uint_as_float(((unsigned)h) << 16);
}

// ---------------------------------------------------------------------------
// Swizzled bf16 LDS tile: 128 rows x 64 bf16 (128 B/row). 16B slot index XOR'd
// with (row&7) -> a "32 lanes read 16 rows at one 16B column" ds_read_b128
// pattern spreads uniformly (8 words/bank). Same function on write and read.
// ---------------------------------------------------------------------------
__device__ __forceinline__ int lds_addr(int row, int byte_in_row) {
  return row * 128 + (byte_in_row & 15) + ((((byte_in_row >> 4) ^ row) & 7) << 4);
}

__device__ __forceinline__ void cvt_write8(char* hi, char* lo, const float* f) {
  union { unsigned short us[8]; uint4 q; } H, L;
  #pragma unroll
  for (int i = 0; i < 8; ++i) {
    unsigned short h = f2bf(f[i]);
    H.us[i] = (short)h;
    L.us[i] = (short)f2bf(f[i] - bf2f(h));
  }
  *(uint4*)hi = H.q;
  *(uint4*)lo = L.q;
}

// ---------------------------------------------------------------------------
// Kernel 1: LayerNorm. One 256-thread block per row of 1024. (unchanged)
// ---------------------------------------------------------------------------
__global__ __launch_bounds__(256) void ln_kernel(const float* __restrict__ x,
                                                 const float* __restrict__ w,
                                                 const float* __restrict__ b,
                                                 float* __restrict__ h) {
  const int row = blockIdx.x;
  const int t = threadIdx.x;
  const float* xr = x + (size_t)row * DIM;
  float4 v = *(const float4*)(xr + t * 4);
  float s  = v.x + v.y + v.z + v.w;
  float s2 = v.x * v.x + v.y * v.y + v.z * v.z + v.w * v.w;
  #pragma unroll
  for (int off = 32; off > 0; off >>= 1) {
    s  += __shfl_down(s, off);
    s2 += __shfl_down(s2, off);
  }
  __shared__ float red[10];
  const int wid = t >> 6;
  if ((t & 63) == 0) { red[wid] = s; red[4 + wid] = s2; }
  __syncthreads();
  if (t == 0) {
    float ts = 0.f, ts2 = 0.f;
    #pragma unroll
    for (int i = 0; i < 4; ++i) { ts += red[i]; ts2 += red[4 + i]; }
    float mu  = ts * (1.0f / DIM);
    float var = ts2 * (1.0f / DIM) - mu * mu;
    red[8] = mu;
    red[9] = rsqrtf(var + 1e-5f);
  }
  __syncthreads();
  const float mu = red[8], rs = red[9];
  float4 wv = *(const float4*)(w + t * 4);
  float4 bv = *(const float4*)(b + t * 4);
  float4 o;
  o.x = (v.x - mu) * rs * wv.x + bv.x;
  o.y = (v.y - mu) * rs * wv.y + bv.y;
  o.z = (v.z - mu) * rs * wv.z + bv.z;
  o.w = (v.w - mu) * rs * wv.w + bv.w;
  *(float4*)(h + (size_t)row * DIM + t * 4) = o;
}

// ---------------------------------------------------------------------------
// Kernel 2/5: bf16x3 MFMA GEMM  C[M][N] = A[M][K]*B[N][K]^T + bias[N].
// fp32 inputs split in-LDS into hi/lo bf16; 3 MFMA passes per k-step:
// hi*hi + hi*lo + lo*hi (lo*lo term ~2^-18 dropped -> ~1e-5 rel error).
// Tile 128x128, BK=64 fp32, 4 waves, each wave a 64x64 quadrant as 4x4
// mfma_f32_16x16x32_bf16 tiles. N must be a multiple of 128; M guarded.
// ---------------------------------------------------------------------------
__global__ __launch_bounds__(256) void gemm_bf16x3(const float* __restrict__ A,
                                                   const float* __restrict__ B,
                                                   const float* __restrict__ bias,
                                                   float* __restrict__ C,
                                                   int M, int N, int K) {
  __shared__ char lds[65536];
  char* Ahi = lds;
  char* Alo = lds + 16384;
  char* Bhi = lds + 32768;
  char* Blo = lds + 49152;

  const int t = threadIdx.x;
  const int l = t & 63;
  const int wid = t >> 6;              // 0..3
  const int wrow = (wid & 1) * 64;     // wave quadrant
  const int wcol = (wid >> 1) * 64;
  const int m0 = blockIdx.x * 128;
  const int n0 = blockIdx.y * 128;

  const f32x4 zero = {0.f, 0.f, 0.f, 0.f};
  f32x4 acc[4][4];
  #pragma unroll
  for (int i = 0; i < 4; ++i)
    #pragma unroll
    for (int j = 0; j < 4; ++j) acc[i][j] = zero;

  const int kc = (t & 7) * 8;          // fp32 col offset of this thread's 8-elem chunk
  const int lrow = (l & 15);
  const int lch = (l >> 4);            // k-chunk 0..3

  for (int k0 = 0; k0 < K; k0 += 64) {
    __syncthreads();
    // ---- stage: load 128x64 fp32 of A and B into regs (issue early) ----
    float va[4][8], vb[4][8];
    #pragma unroll
    for (int p = 0; p < 4; ++p) {
      const int row = p * 32 + (t >> 3);
      const int m = m0 + row;
      if (m < M) {
        const float* pa = A + (size_t)m * K + k0 + kc;
        *(float4*)&va[p][0] = *(const float4*)pa;
        *(float4*)&va[p][4] = *(const float4*)(pa + 4);
      } else {
        #pragma unroll
        for (int i = 0; i < 8; ++i) va[p][i] = 0.f;
      }
      const float* pb = B + (size_t)(n0 + row) * K + k0 + kc;
      *(float4*)&vb[p][0] = *(const float4*)pb;
      *(float4*)&vb[p][4] = *(const float4*)(pb + 4);
    }
    // ---- convert + swizzled LDS write ----
    #pragma unroll
    for (int p = 0; p < 4; ++p) {
      const int row = p * 32 + (t >> 3);
      const int a = lds_addr(row, kc * 2);
      cvt_write8(Ahi + a, Alo + a, va[p]);
      cvt_write8(Bhi + a, Blo + a, vb[p]);
    }
    __syncthreads();
    // ---- MFMA: 2 k-steps of 32, 4x4 tiles, 3 passes ----
    #pragma unroll
    for (int ks = 0; ks < 2; ++ks) {
      const int bycol = ks * 64 + lch * 16;
      bf16x8 ah[4], al[4], bh[4], bl[4];
      #pragma unroll
      for (int rt = 0; rt < 4; ++rt) {
        const int ar = lds_addr(wrow + rt * 16 + lrow, bycol);
        ah[rt] = *(const bf16x8*)(Ahi + ar);
        al[rt] = *(const bf16x8*)(Alo + ar);
        const int br = lds_addr(wcol + rt * 16 + lrow, bycol);
        bh[rt] = *(const bf16x8*)(Bhi + br);
        bl[rt] = *(const bf16x8*)(Blo + br);
      }
      #pragma unroll
      for (int rt = 0; rt < 4; ++rt)
        #pragma unroll
        for (int ct = 0; ct < 4; ++ct) {
          acc[rt][ct] = __builtin_amdgcn_mfma_f32_16x16x32_bf16(ah[rt], bh[ct], acc[rt][ct], 0, 0, 0);
          acc[rt][ct] = __builtin_amdgcn_mfma_f32_16x16x32_bf16(ah[rt], bl[ct], acc[rt][ct], 0, 0, 0);
          acc[rt][ct] = __builtin_amdgcn_mfma_f32_16x16x32_bf16(al[rt], bh[ct], acc[rt][ct], 0, 0, 0);
        }
    }
  }

  // ---- epilogue: C/D map col=lane&15, row=(lane>>4)*4+reg [m89/m91] ----
  #pragma unroll
  for (int rt = 0; rt < 4; ++rt)
    #pragma unroll
    for (int ct = 0; ct < 4; ++ct) {
      const int n = n0 + wcol + ct * 16 + lrow;
      const float bv = bias[n];
      #pragma unroll
      for (int j = 0; j < 4; ++j) {
        const int m = m0 + wrow + rt * 16 + lch * 4 + j;
        if (m < M) C[(size_t)m * N + n] = acc[rt][ct][j] + bv;
      }
    }
}

// ---------------------------------------------------------------------------
// Kernel 3: in-place RoPE on q and k halves of qkv. (unchanged)
// ---------------------------------------------------------------------------
__global__ __launch_bounds__(256) void rope_kernel(float* __restrict__ qkv,
                                                   const int* __restrict__ pos,
                                                   const float* __restrict__ theta) {
  const int id = blockIdx.x * 256 + threadIdx.x;
  if (id >= B_SZ * S_LEN * NH * 32) return;
  const int d  = id & 31;
  const int hh = (id >> 5) & 15;
  const int bs = id >> 9;
  const int p = pos[bs];
  const float th = theta[((size_t)p * NH + hh) * 32 + d];
  float sn, c;
  sincosf(th, &sn, &c);
  const size_t base = (size_t)bs * QKV_DIM + hh * HD + d;
  #pragma unroll
  for (int tt = 0; tt < 2; ++tt) {
    const size_t i1 = base + tt * DIM;       // q at +0, k at +1024
    float x1 = qkv[i1];
    float x2 = qkv[i1 + 32];
    qkv[i1]      = x1 * c - x2 * sn;
    qkv[i1 + 32] = x2 * c + x1 * sn;
  }
}

// ---------------------------------------------------------------------------
// Kernel 4: causal flash attention, fp32 vector ALU. (unchanged)
// ---------------------------------------------------------------------------
__device__ __forceinline__ int sw_idx(int row, int chunk) {
  return row * 64 + ((chunk ^ (row >> 2)) & 15) * 4;
}

__global__ __launch_bounds__(256) void attn_kernel(const float* __restrict__ qkv,
                                                   float* __restrict__ o_out) {
  const int qt = blockIdx.x;       // 0..16
  const int hh = blockIdx.y;       // 0..15
  const int b  = blockIdx.z;       // 0..7
  const int t  = threadIdx.x;
  const int q0 = qt * 64;

  __shared__ float Qs[64 * 64];
  __shared__ float KPs[64 * 64];   // K tile, then reused as P tile
  __shared__ float Vs[64 * 64];

  const int tg = t >> 4;           // row group 0..15
  const int tl = t & 15;           // 0..15
  const int r0 = tg * 4;
  const int c0 = tl * 4;

  const size_t bs_base = (size_t)b * S_LEN * QKV_DIM;

  #pragma unroll
  for (int p = 0; p < 4; ++p) {
    int f = t + p * 256;
    int row = f >> 4;
    int ch = f & 15;
    int s = q0 + row;
    float4 v = make_float4(0.f, 0.f, 0.f, 0.f);
    if (s < S_LEN)
      v = *(const float4*)(qkv + bs_base + (size_t)s * QKV_DIM + hh * HD + ch * 4);
    *(float4*)(Qs + sw_idx(row, ch)) = v;
  }

  float m[4], l[4], acc[4][4];
  #pragma unroll
  for (int i = 0; i < 4; ++i) {
    m[i] = -1e30f; l[i] = 0.f;
    #pragma unroll
    for (int j = 0; j < 4; ++j) acc[i][j] = 0.f;
  }

  const float scale = 0.125f;      // 1/sqrt(64)
  const int kt_max = (q0 + 63 < S_LEN ? q0 + 63 : S_LEN - 1) >> 6;

  for (int kt = 0; kt <= kt_max; ++kt) {
    const int k0 = kt * 64;
    __syncthreads();
    #pragma unroll
    for (int p = 0; p < 4; ++p) {
      int f = t + p * 256;
      int row = f >> 4;
      int ch = f & 15;
      int s = k0 + row;
      float4 kv = make_float4(0.f, 0.f, 0.f, 0.f);
      float4 vv = make_float4(0.f, 0.f, 0.f, 0.f);
      if (s < S_LEN) {
        const float* base = qkv + bs_base + (size_t)s * QKV_DIM + hh * HD + ch * 4;
        kv = *(const float4*)(base + DIM);       // k
        vv = *(const float4*)(base + 2 * DIM);   // v
      }
      *(float4*)(KPs + sw_idx(row, ch)) = kv;
      *(float4*)(Vs  + sw_idx(row, ch)) = vv;
    }
    __syncthreads();

    float sc[4][4];
    #pragma unroll
    for (int i = 0; i < 4; ++i)
      #pragma unroll
      for (int j = 0; j < 4; ++j) sc[i][j] = 0.f;
    #pragma unroll
    for (int d4 = 0; d4 < 16; ++d4) {
      float4 qv[4], kv[4];
      #pragma unroll
      for (int i = 0; i < 4; ++i) qv[i] = *(const float4*)(Qs + sw_idx(r0 + i, d4));
      #pragma unroll
      for (int j = 0; j < 4; ++j) kv[j] = *(const float4*)(KPs + sw_idx(c0 + j, d4));
      #pragma unroll
      for (int i = 0; i < 4; ++i)
        #pragma unroll
        for (int j = 0; j < 4; ++j)
          sc[i][j] += qv[i].x * kv[j].x + qv[i].y * kv[j].y +
                      qv[i].z * kv[j].z + qv[i].w * kv[j].w;
    }

    #pragma unroll
    for (int i = 0; i < 4; ++i) {
      const int qi = q0 + r0 + i;
      #pragma unroll
      for (int j = 0; j < 4; ++j) {
        const int kj = k0 + c0 + j;
        sc[i][j] = (kj <= qi && kj < S_LEN) ? sc[i][j] * scale : -1e30f;
      }
    }

    float tmax[4];
    #pragma unroll
    for (int i = 0; i < 4; ++i)
      tmax[i] = fmaxf(fmaxf(sc[i][0], sc[i][1]), fmaxf(sc[i][2], sc[i][3]));
    #pragma unroll
    for (int off = 1; off < 16; off <<= 1)
      #pragma unroll
      for (int i = 0; i < 4; ++i)
        tmax[i] = fmaxf(tmax[i], __shfl_xor(tmax[i], off, 16));

    float tsum[4], mnew[4];
    #pragma unroll
    for (int i = 0; i < 4; ++i) {
      mnew[i] = fmaxf(m[i], tmax[i]);
      float su = 0.f;
      #pragma unroll
      for (int j = 0; j < 4; ++j) {
        sc[i][j] = __expf(sc[i][j] - mnew[i]);
        su += sc[i][j];
      }
      tsum[i] = su;
    }
    #pragma unroll
    for (int off = 1; off < 16; off <<= 1)
      #pragma unroll
      for (int i = 0; i < 4; ++i) tsum[i] += __shfl_xor(tsum[i], off, 16);
    #pragma unroll
    for (int i = 0; i < 4; ++i) {
      const float co = __expf(m[i] - mnew[i]);
      l[i] = l[i] * co + tsum[i];
      #pragma unroll
      for (int j = 0; j < 4; ++j) acc[i][j] *= co;
      m[i] = mnew[i];
    }

    __syncthreads();
    #pragma unroll
    for (int i = 0; i < 4; ++i) {
      float4 pv = make_float4(sc[i][0], sc[i][1], sc[i][2], sc[i][3]);
      *(float4*)(KPs + sw_idx(r0 + i, tl)) = pv;
    }
    __syncthreads();

    #pragma unroll
    for (int c4 = 0; c4 < 16; ++c4) {
      float4 pv[4];
      #pragma unroll
      for (int i = 0; i < 4; ++i) pv[i] = *(const float4*)(KPs + sw_idx(r0 + i, c4));
      float4 vv[4];
      #pragma unroll
      for (int cc = 0; cc < 4; ++cc) vv[cc] = *(const float4*)(Vs + sw_idx(c4 * 4 + cc, tl));
      #pragma unroll
      for (int i = 0; i < 4; ++i) {
        acc[i][0] += pv[i].x * vv[0].x + pv[i].y * vv[1].x + pv[i].z * vv[2].x + pv[i].w * vv[3].x;
        acc[i][1] += pv[i].x * vv[0].y + pv[i].y * vv[1].y + pv[i].z * vv[2].y + pv[i].w * vv[3].y;
        acc[i][2] += pv[i].x * vv[0].z + pv[i].y * vv[1].z + pv[i].z * vv[2].z + pv[i].w * vv[3].z;
        acc[i][3] += pv[i].x * vv[0].w + pv[i].y * vv[1].w + pv[i].z * vv[2].w + pv[i].w * vv[3].w;
      }
    }
  }

  #pragma unroll
  for (int i = 0; i < 4; ++i) {
    const int s = q0 + r0 + i;
    if (s >= S_LEN) continue;
    const float inv = 1.f / l[i];
    float4 r = make_float4(acc[i][0] * inv, acc[i][1] * inv,
                           acc[i][2] * inv, acc[i][3] * inv);
    *(float4*)(o_out + ((size_t)b * S_LEN + s) * DIM + hh * HD + tl * 4) = r;
  }
}

// ---------------------------------------------------------------------------
extern "C" void kernel_launch(void* const* d_in, const int* in_sizes, int n_in,
                              void* d_out, int out_size, void* d_ws, size_t ws_size,
                              hipStream_t stream) {
  const float* x     = (const float*)d_in[0];
  const int*   pos   = (const int*)d_in[1];
  const float* theta = (const float*)d_in[2];
  const float* ln_w  = (const float*)d_in[3];
  const float* ln_b  = (const float*)d_in[4];
  const float* qkv_w = (const float*)d_in[5];
  const float* qkv_b = (const float*)d_in[6];
  const float* out_w = (const float*)d_in[7];
  const float* out_b = (const float*)d_in[8];
  float* out = (float*)d_out;

  // workspace: h [M,1024] | qkv [M,3072]; attn output aliases h. 134.3 MB.
  float* h   = (float*)d_ws;
  float* qkv = h + (size_t)M_ROWS * DIM;
  float* o   = h;

  ln_kernel<<<M_ROWS, 256, 0, stream>>>(x, ln_w, ln_b, h);
  gemm_bf16x3<<<dim3(65, 24), 256, 0, stream>>>(h, qkv_w, qkv_b, qkv,
                                                M_ROWS, QKV_DIM, DIM);
  rope_kernel<<<(B_SZ * S_LEN * NH * 32 + 255) / 256, 256, 0, stream>>>(qkv, pos, theta);
  attn_kernel<<<dim3(17, NH, B_SZ), 256, 0, stream>>>(qkv, o);
  gemm_bf16x3<<<dim3(65, 8), 256, 0, stream>>>(o, out_w, out_b, out,
                                               M_ROWS, DIM, DIM);
}

// Round 7
// 632.163 us; speedup vs baseline: 4.9326x; 4.9326x over previous
//
#include <hip/hip_runtime.h>
#include <math.h>

#define B_SZ 8
#define S_LEN 1025
#define DIM 1024
#define NH 16
#define HD 64
#define QKV_DIM 3072
#define M_ROWS (B_SZ * S_LEN)   // 8200

typedef __attribute__((ext_vector_type(8))) short bf16x8;
typedef __attribute__((ext_vector_type(4))) float f32x4;

// ---------------------------------------------------------------------------
// fp32 -> bf16 (RNE) split helpers: x ~= hi + lo, |x-hi-lo| <= ~2^-18 |x|.
// (validated on HW in round 5: gemm_bf16x3 passed with absmax 1.22e-4)
// ---------------------------------------------------------------------------
__device__ __forceinline__ unsigned short f2bf(float x) {
  unsigned u = __float_as_uint(x);
  unsigned r = u + 0x7FFFu + ((u >> 16) & 1u);
  return (unsigned short)(r >> 16);
}
__device__ __forceinline__ float bf2f(unsigned short h) {
  return __uint_as_float(((unsigned)h) << 16);
}

// Swizzled bf16 LDS tile, 128 B/row: byte = row*128 + (b&15) + (((b>>4)^row)&7)<<4.
// Any "16 consecutive lanes read 16 rows at one 16B column" b128 access is
// conflict-free (8-lane phases cover all 32 banks). Same function write+read.
__device__ __forceinline__ int lds_addr(int row, int byte_in_row) {
  return row * 128 + (byte_in_row & 15) + ((((byte_in_row >> 4) ^ row) & 7) << 4);
}

__device__ __forceinline__ void cvt_write8(char* hi, char* lo, const float* f) {
  union { unsigned short us[8]; uint4 q; } H, L;
  #pragma unroll
  for (int i = 0; i < 8; ++i) {
    unsigned short h = f2bf(f[i]);
    H.us[i] = h;
    L.us[i] = f2bf(f[i] - bf2f(h));
  }
  *(uint4*)hi = H.q;
  *(uint4*)lo = L.q;
}

// ---------------------------------------------------------------------------
// Kernel 1: LayerNorm. (unchanged)
// ---------------------------------------------------------------------------
__global__ __launch_bounds__(256) void ln_kernel(const float* __restrict__ x,
                                                 const float* __restrict__ w,
                                                 const float* __restrict__ b,
                                                 float* __restrict__ h) {
  const int row = blockIdx.x;
  const int t = threadIdx.x;
  const float* xr = x + (size_t)row * DIM;
  float4 v = *(const float4*)(xr + t * 4);
  float s  = v.x + v.y + v.z + v.w;
  float s2 = v.x * v.x + v.y * v.y + v.z * v.z + v.w * v.w;
  #pragma unroll
  for (int off = 32; off > 0; off >>= 1) {
    s  += __shfl_down(s, off);
    s2 += __shfl_down(s2, off);
  }
  __shared__ float red[10];
  const int wid = t >> 6;
  if ((t & 63) == 0) { red[wid] = s; red[4 + wid] = s2; }
  __syncthreads();
  if (t == 0) {
    float ts = 0.f, ts2 = 0.f;
    #pragma unroll
    for (int i = 0; i < 4; ++i) { ts += red[i]; ts2 += red[4 + i]; }
    float mu  = ts * (1.0f / DIM);
    float var = ts2 * (1.0f / DIM) - mu * mu;
    red[8] = mu;
    red[9] = rsqrtf(var + 1e-5f);
  }
  __syncthreads();
  const float mu = red[8], rs = red[9];
  float4 wv = *(const float4*)(w + t * 4);
  float4 bv = *(const float4*)(b + t * 4);
  float4 o;
  o.x = (v.x - mu) * rs * wv.x + bv.x;
  o.y = (v.y - mu) * rs * wv.y + bv.y;
  o.z = (v.z - mu) * rs * wv.z + bv.z;
  o.w = (v.w - mu) * rs * wv.w + bv.w;
  *(float4*)(h + (size_t)row * DIM + t * 4) = o;
}

// ---------------------------------------------------------------------------
// Kernel 2/5: bf16x3 MFMA GEMM (unchanged, HW-validated round 5)
// ---------------------------------------------------------------------------
__global__ __launch_bounds__(256) void gemm_bf16x3(const float* __restrict__ A,
                                                   const float* __restrict__ B,
                                                   const float* __restrict__ bias,
                                                   float* __restrict__ C,
                                                   int M, int N, int K) {
  __shared__ char lds[65536];
  char* Ahi = lds;
  char* Alo = lds + 16384;
  char* Bhi = lds + 32768;
  char* Blo = lds + 49152;

  const int t = threadIdx.x;
  const int l = t & 63;
  const int wid = t >> 6;              // 0..3
  const int wrow = (wid & 1) * 64;     // wave quadrant
  const int wcol = (wid >> 1) * 64;
  const int m0 = blockIdx.x * 128;
  const int n0 = blockIdx.y * 128;

  const f32x4 zero = {0.f, 0.f, 0.f, 0.f};
  f32x4 acc[4][4];
  #pragma unroll
  for (int i = 0; i < 4; ++i)
    #pragma unroll
    for (int j = 0; j < 4; ++j) acc[i][j] = zero;

  const int kc = (t & 7) * 8;
  const int lrow = (l & 15);
  const int lch = (l >> 4);

  for (int k0 = 0; k0 < K; k0 += 64) {
    __syncthreads();
    float va[4][8], vb[4][8];
    #pragma unroll
    for (int p = 0; p < 4; ++p) {
      const int row = p * 32 + (t >> 3);
      const int m = m0 + row;
      if (m < M) {
        const float* pa = A + (size_t)m * K + k0 + kc;
        *(float4*)&va[p][0] = *(const float4*)pa;
        *(float4*)&va[p][4] = *(const float4*)(pa + 4);
      } else {
        #pragma unroll
        for (int i = 0; i < 8; ++i) va[p][i] = 0.f;
      }
      const float* pb = B + (size_t)(n0 + row) * K + k0 + kc;
      *(float4*)&vb[p][0] = *(const float4*)pb;
      *(float4*)&vb[p][4] = *(const float4*)(pb + 4);
    }
    #pragma unroll
    for (int p = 0; p < 4; ++p) {
      const int row = p * 32 + (t >> 3);
      const int a = lds_addr(row, kc * 2);
      cvt_write8(Ahi + a, Alo + a, va[p]);
      cvt_write8(Bhi + a, Blo + a, vb[p]);
    }
    __syncthreads();
    #pragma unroll
    for (int ks = 0; ks < 2; ++ks) {
      const int bycol = ks * 64 + lch * 16;
      bf16x8 ah[4], al[4], bh[4], bl[4];
      #pragma unroll
      for (int rt = 0; rt < 4; ++rt) {
        const int ar = lds_addr(wrow + rt * 16 + lrow, bycol);
        ah[rt] = *(const bf16x8*)(Ahi + ar);
        al[rt] = *(const bf16x8*)(Alo + ar);
        const int br = lds_addr(wcol + rt * 16 + lrow, bycol);
        bh[rt] = *(const bf16x8*)(Bhi + br);
        bl[rt] = *(const bf16x8*)(Blo + br);
      }
      #pragma unroll
      for (int rt = 0; rt < 4; ++rt)
        #pragma unroll
        for (int ct = 0; ct < 4; ++ct) {
          acc[rt][ct] = __builtin_amdgcn_mfma_f32_16x16x32_bf16(ah[rt], bh[ct], acc[rt][ct], 0, 0, 0);
          acc[rt][ct] = __builtin_amdgcn_mfma_f32_16x16x32_bf16(ah[rt], bl[ct], acc[rt][ct], 0, 0, 0);
          acc[rt][ct] = __builtin_amdgcn_mfma_f32_16x16x32_bf16(al[rt], bh[ct], acc[rt][ct], 0, 0, 0);
        }
    }
  }

  #pragma unroll
  for (int rt = 0; rt < 4; ++rt)
    #pragma unroll
    for (int ct = 0; ct < 4; ++ct) {
      const int n = n0 + wcol + ct * 16 + lrow;
      const float bv = bias[n];
      #pragma unroll
      for (int j = 0; j < 4; ++j) {
        const int m = m0 + wrow + rt * 16 + lch * 4 + j;
        if (m < M) C[(size_t)m * N + n] = acc[rt][ct][j] + bv;
      }
    }
}

// ---------------------------------------------------------------------------
// Kernel 3: in-place RoPE. (unchanged)
// ---------------------------------------------------------------------------
__global__ __launch_bounds__(256) void rope_kernel(float* __restrict__ qkv,
                                                   const int* __restrict__ pos,
                                                   const float* __restrict__ theta) {
  const int id = blockIdx.x * 256 + threadIdx.x;
  if (id >= B_SZ * S_LEN * NH * 32) return;
  const int d  = id & 31;
  const int hh = (id >> 5) & 15;
  const int bs = id >> 9;
  const int p = pos[bs];
  const float th = theta[((size_t)p * NH + hh) * 32 + d];
  float sn, c;
  sincosf(th, &sn, &c);
  const size_t base = (size_t)bs * QKV_DIM + hh * HD + d;
  #pragma unroll
  for (int tt = 0; tt < 2; ++tt) {
    const size_t i1 = base + tt * DIM;
    float x1 = qkv[i1];
    float x2 = qkv[i1 + 32];
    qkv[i1]      = x1 * c - x2 * sn;
    qkv[i1 + 32] = x2 * c + x1 * sn;
  }
}

// ---------------------------------------------------------------------------
// Kernel 4: causal flash attention, bf16x3 MFMA (rewrite — was fp32 VALU and
// spilled ~1.5 GB scratch/dispatch at 256 VGPR, 10% occupancy, 2.7 ms).
// Block = 256 thr = 4 waves = one (b, h, 64-row q tile); wave w owns rows
// [16w,16w+16). Q frags in registers (pre-scaled 1/8). K and V^T staged hi/lo
// bf16 in LDS per 64-col k-tile; P staged hi/lo per-wave between QK^T and PV.
// Frag/layout conventions identical to the validated gemm_bf16x3.
// ---------------------------------------------------------------------------
__global__ __launch_bounds__(256) void attn_mfma(const float* __restrict__ qkv,
                                                 float* __restrict__ o_out) {
  const int qt = blockIdx.x;       // 0..16
  const int hh = blockIdx.y;       // 0..15
  const int b  = blockIdx.z;       // 0..7
  const int t  = threadIdx.x;
  const int l  = t & 63;
  const int w  = t >> 6;           // wave 0..3
  const int q0 = qt * 64;
  const int lrow = l & 15;
  const int lch  = l >> 4;         // 0..3

  __shared__ char lds[49152];
  char* Khi  = lds;                // [64][64] bf16, 8 KB each
  char* Klo  = lds + 8192;
  char* Vthi = lds + 16384;        // transposed: row = dim d, col = kv
  char* Vtlo = lds + 24576;
  char* Phi  = lds + 32768;        // row = block-local q row (w*16+...)
  char* Plo  = lds + 40960;

  const size_t bs_base = (size_t)b * S_LEN * QKV_DIM;

  // ---- Q frags in registers: row = w*16+lrow, k-elems lch*8 (+32*ks). ----
  // Pre-scale by 1/sqrt(64)=0.125 (power of 2: exact in both bf16 halves).
  bf16x8 qh[2], ql[2];
  {
    const int qrow = q0 + w * 16 + lrow;
    #pragma unroll
    for (int ks = 0; ks < 2; ++ks) {
      float f[8];
      if (qrow < S_LEN) {
        const float* p = qkv + bs_base + (size_t)qrow * QKV_DIM + hh * HD + ks * 32 + lch * 8;
        *(float4*)&f[0] = *(const float4*)p;
        *(float4*)&f[4] = *(const float4*)(p + 4);
      } else {
        #pragma unroll
        for (int i = 0; i < 8; ++i) f[i] = 0.f;
      }
      union { unsigned short us[8]; bf16x8 v; } H, L;
      #pragma unroll
      for (int i = 0; i < 8; ++i) {
        const float x = f[i] * 0.125f;
        unsigned short hi = f2bf(x);
        H.us[i] = hi;
        L.us[i] = f2bf(x - bf2f(hi));
      }
      qh[ks] = H.v;
      ql[ks] = L.v;
    }
  }

  const f32x4 zero = {0.f, 0.f, 0.f, 0.f};
  f32x4 acc[4];                    // O tile: col d = lrow+16ct, row q = lch*4+j
  float m[4], lsum[4];
  #pragma unroll
  for (int ct = 0; ct < 4; ++ct) acc[ct] = zero;
  #pragma unroll
  for (int j = 0; j < 4; ++j) { m[j] = -1e30f; lsum[j] = 0.f; }

  const int kt_max = (q0 + 63 < S_LEN ? q0 + 63 : S_LEN - 1) >> 6;
  const int sr = t >> 2;           // staging row 0..63
  const int sg = t & 3;            // staging col group (16 floats)

  for (int kt = 0; kt <= kt_max; ++kt) {
    const int k0 = kt * 64;
    __syncthreads();               // prior iter done with K/Vt
    // ---- stage K (row-major) and V (transposed), hi/lo bf16 ----
    {
      float kf[16], vf[16];
      const int s = k0 + sr;
      if (s < S_LEN) {
        const float* base = qkv + bs_base + (size_t)s * QKV_DIM + hh * HD + sg * 16;
        #pragma unroll
        for (int q = 0; q < 4; ++q) {
          *(float4*)&kf[q * 4] = *(const float4*)(base + DIM + q * 4);
          *(float4*)&vf[q * 4] = *(const float4*)(base + 2 * DIM + q * 4);
        }
      } else {
        #pragma unroll
        for (int i = 0; i < 16; ++i) { kf[i] = 0.f; vf[i] = 0.f; }
      }
      const int a0 = lds_addr(sr, sg * 32);
      const int a1 = lds_addr(sr, sg * 32 + 16);
      cvt_write8(Khi + a0, Klo + a0, kf);
      cvt_write8(Khi + a1, Klo + a1, kf + 8);
      #pragma unroll
      for (int i = 0; i < 16; ++i) {
        const int ad = lds_addr(sg * 16 + i, sr * 2);
        unsigned short hi = f2bf(vf[i]);
        *(unsigned short*)(Vthi + ad) = hi;
        *(unsigned short*)(Vtlo + ad) = f2bf(vf[i] - bf2f(hi));
      }
    }
    __syncthreads();

    // ---- scores: sc[ct] = (Q/8) · K^T, bf16x3 ----
    f32x4 sc[4];
    #pragma unroll
    for (int ct = 0; ct < 4; ++ct) {
      f32x4 s = zero;
      #pragma unroll
      for (int ks = 0; ks < 2; ++ks) {
        const int off = lds_addr(ct * 16 + lrow, ks * 64 + lch * 16);
        bf16x8 kh = *(const bf16x8*)(Khi + off);
        bf16x8 kl = *(const bf16x8*)(Klo + off);
        s = __builtin_amdgcn_mfma_f32_16x16x32_bf16(qh[ks], kh, s, 0, 0, 0);
        s = __builtin_amdgcn_mfma_f32_16x16x32_bf16(qh[ks], kl, s, 0, 0, 0);
        s = __builtin_amdgcn_mfma_f32_16x16x32_bf16(ql[ks], kh, s, 0, 0, 0);
      }
      sc[ct] = s;
    }

    // ---- causal mask (D-layout: row q = lch*4+j, col kv = lrow+16ct) ----
    #pragma unroll
    for (int ct = 0; ct < 4; ++ct) {
      const int kj = k0 + lrow + ct * 16;
      #pragma unroll
      for (int j = 0; j < 4; ++j) {
        const int qi = q0 + w * 16 + lch * 4 + j;
        if (kj > qi) sc[ct][j] = -1e30f;
      }
    }

    // ---- online softmax (row groups = 16 contiguous lanes, same lch) ----
    float tmax[4];
    #pragma unroll
    for (int j = 0; j < 4; ++j)
      tmax[j] = fmaxf(fmaxf(sc[0][j], sc[1][j]), fmaxf(sc[2][j], sc[3][j]));
    #pragma unroll
    for (int off = 1; off < 16; off <<= 1)
      #pragma unroll
      for (int j = 0; j < 4; ++j)
        tmax[j] = fmaxf(tmax[j], __shfl_xor(tmax[j], off, 16));

    float mnew[4], tsum[4];
    #pragma unroll
    for (int j = 0; j < 4; ++j) {
      mnew[j] = fmaxf(m[j], tmax[j]);
      float su = 0.f;
      #pragma unroll
      for (int ct = 0; ct < 4; ++ct) {
        sc[ct][j] = __expf(sc[ct][j] - mnew[j]);
        su += sc[ct][j];
      }
      tsum[j] = su;
    }
    #pragma unroll
    for (int off = 1; off < 16; off <<= 1)
      #pragma unroll
      for (int j = 0; j < 4; ++j) tsum[j] += __shfl_xor(tsum[j], off, 16);
    #pragma unroll
    for (int j = 0; j < 4; ++j) {
      const float co = __expf(m[j] - mnew[j]);
      lsum[j] = lsum[j] * co + tsum[j];
      #pragma unroll
      for (int ct = 0; ct < 4; ++ct) acc[ct][j] *= co;
      m[j] = mnew[j];
    }

    // ---- write P hi/lo to this wave's LDS region ----
    #pragma unroll
    for (int ct = 0; ct < 4; ++ct)
      #pragma unroll
      for (int j = 0; j < 4; ++j) {
        const float pv = sc[ct][j];
        const int ad = lds_addr(w * 16 + lch * 4 + j, (lrow + ct * 16) * 2);
        unsigned short hi = f2bf(pv);
        *(unsigned short*)(Phi + ad) = hi;
        *(unsigned short*)(Plo + ad) = f2bf(pv - bf2f(hi));
      }
    __syncthreads();               // P visible (and all waves aligned)

    // ---- PV: acc[ct] += P · V (A=P rows q, B=V^T rows d), bf16x3 ----
    #pragma unroll
    for (int ks = 0; ks < 2; ++ks) {
      const int poff = lds_addr(w * 16 + lrow, ks * 64 + lch * 16);
      bf16x8 ph = *(const bf16x8*)(Phi + poff);
      bf16x8 pl = *(const bf16x8*)(Plo + poff);
      #pragma unroll
      for (int ct = 0; ct < 4; ++ct) {
        const int voff = lds_addr(ct * 16 + lrow, ks * 64 + lch * 16);
        bf16x8 vh = *(const bf16x8*)(Vthi + voff);
        bf16x8 vl = *(const bf16x8*)(Vtlo + voff);
        acc[ct] = __builtin_amdgcn_mfma_f32_16x16x32_bf16(ph, vh, acc[ct], 0, 0, 0);
        acc[ct] = __builtin_amdgcn_mfma_f32_16x16x32_bf16(ph, vl, acc[ct], 0, 0, 0);
        acc[ct] = __builtin_amdgcn_mfma_f32_16x16x32_bf16(pl, vh, acc[ct], 0, 0, 0);
      }
    }
  }

  // ---- epilogue ----
  #pragma unroll
  for (int j = 0; j < 4; ++j) {
    const int s = q0 + w * 16 + lch * 4 + j;
    if (s >= S_LEN) continue;
    const float inv = 1.f / lsum[j];
    #pragma unroll
    for (int ct = 0; ct < 4; ++ct)
      o_out[((size_t)b * S_LEN + s) * DIM + hh * HD + lrow + ct * 16] = acc[ct][j] * inv;
  }
}

// ---------------------------------------------------------------------------
extern "C" void kernel_launch(void* const* d_in, const int* in_sizes, int n_in,
                              void* d_out, int out_size, void* d_ws, size_t ws_size,
                              hipStream_t stream) {
  const float* x     = (const float*)d_in[0];
  const int*   pos   = (const int*)d_in[1];
  const float* theta = (const float*)d_in[2];
  const float* ln_w  = (const float*)d_in[3];
  const float* ln_b  = (const float*)d_in[4];
  const float* qkv_w = (const float*)d_in[5];
  const float* qkv_b = (const float*)d_in[6];
  const float* out_w = (const float*)d_in[7];
  const float* out_b = (const float*)d_in[8];
  float* out = (float*)d_out;

  // workspace: h [M,1024] | qkv [M,3072]; attn output aliases h. 134.3 MB.
  float* h   = (float*)d_ws;
  float* qkv = h + (size_t)M_ROWS * DIM;
  float* o   = h;

  ln_kernel<<<M_ROWS, 256, 0, stream>>>(x, ln_w, ln_b, h);
  gemm_bf16x3<<<dim3(65, 24), 256, 0, stream>>>(h, qkv_w, qkv_b, qkv,
                                                M_ROWS, QKV_DIM, DIM);
  rope_kernel<<<(B_SZ * S_LEN * NH * 32 + 255) / 256, 256, 0, stream>>>(qkv, pos, theta);
  attn_mfma<<<dim3(17, NH, B_SZ), 256, 0, stream>>>(qkv, o);
  gemm_bf16x3<<<dim3(65, 8), 256, 0, stream>>>(o, out_w, out_b, out,
                                               M_ROWS, DIM, DIM);
}

// Round 11
// 632.000 us; speedup vs baseline: 4.9339x; 1.0003x over previous
//
#include <hip/hip_runtime.h>
#include <hip/hip_bf16.h>
#include <math.h>

#define B_SZ 8
#define S_LEN 1025
#define DIM 1024
#define NH 16
#define HD 64
#define QKV_DIM 3072
#define M_ROWS (B_SZ * S_LEN)   // 8200

typedef __attribute__((ext_vector_type(8))) short bf16x8;
typedef __attribute__((ext_vector_type(4))) float f32x4;
typedef unsigned short u16;

// ---------------------------------------------------------------------------
// hi/lo bf16 split (x ~= hi + lo, error ~2^-18 |x|). Compiler casts -> packs
// into v_cvt_pk_bf16_f32 (vs ~10 inst/float for manual bit math).
// Error class HW-validated round 5/7 (absmax 1.22e-4).
// ---------------------------------------------------------------------------
__device__ __forceinline__ void bsplit(float x, u16& hi, u16& lo) {
  __hip_bfloat16 bh = __float2bfloat16(x);
  __builtin_memcpy(&hi, &bh, 2);
  __hip_bfloat16 bl = __float2bfloat16(x - __bfloat162float(bh));
  __builtin_memcpy(&lo, &bl, 2);
}
__device__ __forceinline__ float bf2f(u16 h) {
  return __uint_as_float(((unsigned)h) << 16);
}

// Swizzled bf16 LDS tile, 128 B/row (HW-validated rounds 5/7):
// byte = row*128 + (b&15) + (((b>>4)^row)&7)<<4. Same function write+read.
__device__ __forceinline__ int lds_addr(int row, int byte_in_row) {
  return row * 128 + (byte_in_row & 15) + ((((byte_in_row >> 4) ^ row) & 7) << 4);
}

__device__ __forceinline__ void split_write8(char* hi, char* lo, const float* f) {
  union { u16 us[8]; uint4 q; } H, L;
  #pragma unroll
  for (int i = 0; i < 8; ++i) bsplit(f[i], H.us[i], L.us[i]);
  *(uint4*)hi = H.q;
  *(uint4*)lo = L.q;
}

// ---------------------------------------------------------------------------
// Kernel 1: LayerNorm -> h hi/lo planes (consumers never re-convert).
// ---------------------------------------------------------------------------
__global__ __launch_bounds__(256) void ln_kernel(const float* __restrict__ x,
                                                 const float* __restrict__ w,
                                                 const float* __restrict__ b,
                                                 u16* __restrict__ h_hi,
                                                 u16* __restrict__ h_lo) {
  const int row = blockIdx.x;
  const int t = threadIdx.x;
  const float* xr = x + (size_t)row * DIM;
  float4 v = *(const float4*)(xr + t * 4);
  float s  = v.x + v.y + v.z + v.w;
  float s2 = v.x * v.x + v.y * v.y + v.z * v.z + v.w * v.w;
  #pragma unroll
  for (int off = 32; off > 0; off >>= 1) {
    s  += __shfl_down(s, off);
    s2 += __shfl_down(s2, off);
  }
  __shared__ float red[10];
  const int wid = t >> 6;
  if ((t & 63) == 0) { red[wid] = s; red[4 + wid] = s2; }
  __syncthreads();
  if (t == 0) {
    float ts = 0.f, ts2 = 0.f;
    #pragma unroll
    for (int i = 0; i < 4; ++i) { ts += red[i]; ts2 += red[4 + i]; }
    float mu  = ts * (1.0f / DIM);
    float var = ts2 * (1.0f / DIM) - mu * mu;
    red[8] = mu;
    red[9] = rsqrtf(var + 1e-5f);
  }
  __syncthreads();
  const float mu = red[8], rs = red[9];
  float4 wv = *(const float4*)(w + t * 4);
  float4 bv = *(const float4*)(b + t * 4);
  float o[4];
  o[0] = (v.x - mu) * rs * wv.x + bv.x;
  o[1] = (v.y - mu) * rs * wv.y + bv.y;
  o[2] = (v.z - mu) * rs * wv.z + bv.z;
  o[3] = (v.w - mu) * rs * wv.w + bv.w;
  union { u16 us[4]; uint2 q; } H, L;
  #pragma unroll
  for (int i = 0; i < 4; ++i) bsplit(o[i], H.us[i], L.us[i]);
  *(uint2*)(h_hi + (size_t)row * DIM + t * 4) = H.q;
  *(uint2*)(h_lo + (size_t)row * DIM + t * 4) = L.q;
}

// ---------------------------------------------------------------------------
// Kernel 2/5: bf16x3 MFMA GEMM, A pre-split planes (pure-copy staging),
// B fp32 split in-kernel (fast cast). MFMA loop / LDS layout / C-D map
// byte-identical to the HW-validated round-5 kernel.
// PLANES_OUT: write C as hi/lo planes (QKV) vs fp32 (out-proj).
// ---------------------------------------------------------------------------
template <bool PLANES_OUT>
__global__ __launch_bounds__(256) void gemm_ps(const u16* __restrict__ Ahi_g,
                                               const u16* __restrict__ Alo_g,
                                               const float* __restrict__ B,
                                               const float* __restrict__ bias,
                                               float* __restrict__ Cf,
                                               u16* __restrict__ Chi,
                                               u16* __restrict__ Clo,
                                               int M, int N, int K) {
  __shared__ char lds[65536];
  char* Ahi = lds;
  char* Alo = lds + 16384;
  char* Bhi = lds + 32768;
  char* Blo = lds + 49152;

  const int t = threadIdx.x;
  const int l = t & 63;
  const int wid = t >> 6;              // 0..3
  const int wrow = (wid & 1) * 64;
  const int wcol = (wid >> 1) * 64;
  const int m0 = blockIdx.x * 128;
  const int n0 = blockIdx.y * 128;

  const f32x4 zero = {0.f, 0.f, 0.f, 0.f};
  f32x4 acc[4][4];
  #pragma unroll
  for (int i = 0; i < 4; ++i)
    #pragma unroll
    for (int j = 0; j < 4; ++j) acc[i][j] = zero;

  const int kc = (t & 7) * 8;
  const int lrow = (l & 15);
  const int lch = (l >> 4);

  for (int k0 = 0; k0 < K; k0 += 64) {
    __syncthreads();
    // ---- A: copy pre-split planes straight into LDS (no conversion) ----
    #pragma unroll
    for (int p = 0; p < 4; ++p) {
      const int row = p * 32 + (t >> 3);
      const int m = m0 + row;
      uint4 vh = make_uint4(0, 0, 0, 0), vl = make_uint4(0, 0, 0, 0);
      if (m < M) {
        const size_t off = (size_t)m * K + k0 + kc;
        vh = *(const uint4*)(Ahi_g + off);
        vl = *(const uint4*)(Alo_g + off);
      }
      const int a = lds_addr(row, kc * 2);
      *(uint4*)(Ahi + a) = vh;
      *(uint4*)(Alo + a) = vl;
    }
    // ---- B: fp32 load + fast-cast split ----
    #pragma unroll
    for (int p = 0; p < 4; ++p) {
      const int row = p * 32 + (t >> 3);
      float vb[8];
      const float* pb = B + (size_t)(n0 + row) * K + k0 + kc;
      *(float4*)&vb[0] = *(const float4*)pb;
      *(float4*)&vb[4] = *(const float4*)(pb + 4);
      const int a = lds_addr(row, kc * 2);
      split_write8(Bhi + a, Blo + a, vb);
    }
    __syncthreads();
    #pragma unroll
    for (int ks = 0; ks < 2; ++ks) {
      const int bycol = ks * 64 + lch * 16;
      bf16x8 ah[4], al[4], bh[4], bl[4];
      #pragma unroll
      for (int rt = 0; rt < 4; ++rt) {
        const int ar = lds_addr(wrow + rt * 16 + lrow, bycol);
        ah[rt] = *(const bf16x8*)(Ahi + ar);
        al[rt] = *(const bf16x8*)(Alo + ar);
        const int br = lds_addr(wcol + rt * 16 + lrow, bycol);
        bh[rt] = *(const bf16x8*)(Bhi + br);
        bl[rt] = *(const bf16x8*)(Blo + br);
      }
      #pragma unroll
      for (int rt = 0; rt < 4; ++rt)
        #pragma unroll
        for (int ct = 0; ct < 4; ++ct) {
          acc[rt][ct] = __builtin_amdgcn_mfma_f32_16x16x32_bf16(ah[rt], bh[ct], acc[rt][ct], 0, 0, 0);
          acc[rt][ct] = __builtin_amdgcn_mfma_f32_16x16x32_bf16(ah[rt], bl[ct], acc[rt][ct], 0, 0, 0);
          acc[rt][ct] = __builtin_amdgcn_mfma_f32_16x16x32_bf16(al[rt], bh[ct], acc[rt][ct], 0, 0, 0);
        }
    }
  }

  // ---- epilogue: C/D map col=lane&15, row=(lane>>4)*4+reg ----
  #pragma unroll
  for (int rt = 0; rt < 4; ++rt)
    #pragma unroll
    for (int ct = 0; ct < 4; ++ct) {
      const int n = n0 + wcol + ct * 16 + lrow;
      const float bv = bias[n];
      #pragma unroll
      for (int j = 0; j < 4; ++j) {
        const int m = m0 + wrow + rt * 16 + lch * 4 + j;
        if (m >= M) continue;
        const float val = acc[rt][ct][j] + bv;
        const size_t idx = (size_t)m * N + n;
        if (PLANES_OUT) {
          u16 hu, lu;
          bsplit(val, hu, lu);
          Chi[idx] = hu;
          Clo[idx] = lu;
        } else {
          Cf[idx] = val;
        }
      }
    }
}

// ---------------------------------------------------------------------------
// Kernel 3: in-place RoPE on q,k hi/lo planes (hi+lo reconstruct is exact).
// ---------------------------------------------------------------------------
__global__ __launch_bounds__(256) void rope_planes(u16* __restrict__ qkv_hi,
                                                   u16* __restrict__ qkv_lo,
                                                   const int* __restrict__ pos,
                                                   const float* __restrict__ theta) {
  const int id = blockIdx.x * 256 + threadIdx.x;
  if (id >= B_SZ * S_LEN * NH * 32) return;
  const int d  = id & 31;
  const int hh = (id >> 5) & 15;
  const int bs = id >> 9;
  const int p = pos[bs];
  const float th = theta[((size_t)p * NH + hh) * 32 + d];
  float sn, c;
  sincosf(th, &sn, &c);
  const size_t base = (size_t)bs * QKV_DIM + hh * HD + d;
  #pragma unroll
  for (int tt = 0; tt < 2; ++tt) {
    const size_t i1 = base + tt * DIM;       // q at +0, k at +1024
    const float x1 = bf2f(qkv_hi[i1]) + bf2f(qkv_lo[i1]);
    const float x2 = bf2f(qkv_hi[i1 + 32]) + bf2f(qkv_lo[i1 + 32]);
    const float y1 = x1 * c - x2 * sn;
    const float y2 = x2 * c + x1 * sn;
    bsplit(y1, qkv_hi[i1], qkv_lo[i1]);
    bsplit(y2, qkv_hi[i1 + 32], qkv_lo[i1 + 32]);
  }
}

// ---------------------------------------------------------------------------
// Kernel 4: causal flash attention, bf16x3 MFMA, consuming pre-split planes
// (staging = pure copies, zero conversion). Structure identical to round-5
// attn_mfma; Q scale 1/8 moved to exact post-MFMA multiply. Emits o planes.
// ---------------------------------------------------------------------------
__global__ __launch_bounds__(256) void attn_mfma(const u16* __restrict__ qkv_hi,
                                                 const u16* __restrict__ qkv_lo,
                                                 u16* __restrict__ o_hi,
                                                 u16* __restrict__ o_lo) {
  const int qt = blockIdx.x;       // 0..16
  const int hh = blockIdx.y;       // 0..15
  const int b  = blockIdx.z;       // 0..7
  const int t  = threadIdx.x;
  const int l  = t & 63;
  const int w  = t >> 6;           // wave 0..3
  const int q0 = qt * 64;
  const int lrow = l & 15;
  const int lch  = l >> 4;         // 0..3

  __shared__ char lds[49152];
  char* Khi  = lds;                // [64][64] bf16, 8 KB each
  char* Klo  = lds + 8192;
  char* Vthi = lds + 16384;        // transposed: row = dim d, col = kv
  char* Vtlo = lds + 24576;
  char* Phi  = lds + 32768;        // row = block-local q row
  char* Plo  = lds + 40960;

  const size_t bs_base = (size_t)b * S_LEN * QKV_DIM;

  // ---- Q frags: direct plane loads (row = w*16+lrow, 8 k-elems each) ----
  bf16x8 qh[2], ql[2];
  {
    const int qrow = q0 + w * 16 + lrow;
    #pragma unroll
    for (int ks = 0; ks < 2; ++ks) {
      if (qrow < S_LEN) {
        const size_t off = bs_base + (size_t)qrow * QKV_DIM + hh * HD + ks * 32 + lch * 8;
        qh[ks] = *(const bf16x8*)(qkv_hi + off);
        ql[ks] = *(const bf16x8*)(qkv_lo + off);
      } else {
        qh[ks] = (bf16x8)(short)0;
        ql[ks] = (bf16x8)(short)0;
      }
    }
  }

  const f32x4 zero = {0.f, 0.f, 0.f, 0.f};
  f32x4 acc[4];                    // O: col d = lrow+16ct, row q = lch*4+j
  float m[4], lsum[4];
  #pragma unroll
  for (int ct = 0; ct < 4; ++ct) acc[ct] = zero;
  #pragma unroll
  for (int j = 0; j < 4; ++j) { m[j] = -1e30f; lsum[j] = 0.f; }

  const int kt_max = (q0 + 63 < S_LEN ? q0 + 63 : S_LEN - 1) >> 6;
  const int sr = t >> 2;           // staging row 0..63
  const int sg = t & 3;            // staging col group (16 elems)

  for (int kt = 0; kt <= kt_max; ++kt) {
    const int k0 = kt * 64;
    __syncthreads();               // prior iter done with K/Vt
    // ---- stage K (row-major) and V (transposed): pure copies ----
    {
      uint4 kh0 = make_uint4(0,0,0,0), kh1 = kh0, kl0 = kh0, kl1 = kh0;
      union { uint4 q[2]; u16 us[16]; } VH, VL;
      VH.q[0] = VH.q[1] = VL.q[0] = VL.q[1] = make_uint4(0,0,0,0);
      const int s = k0 + sr;
      if (s < S_LEN) {
        const size_t off = bs_base + (size_t)s * QKV_DIM + hh * HD + sg * 16;
        kh0 = *(const uint4*)(qkv_hi + off + DIM);
        kh1 = *(const uint4*)(qkv_hi + off + DIM + 8);
        kl0 = *(const uint4*)(qkv_lo + off + DIM);
        kl1 = *(const uint4*)(qkv_lo + off + DIM + 8);
        VH.q[0] = *(const uint4*)(qkv_hi + off + 2 * DIM);
        VH.q[1] = *(const uint4*)(qkv_hi + off + 2 * DIM + 8);
        VL.q[0] = *(const uint4*)(qkv_lo + off + 2 * DIM);
        VL.q[1] = *(const uint4*)(qkv_lo + off + 2 * DIM + 8);
      }
      const int a0 = lds_addr(sr, sg * 32);
      const int a1 = lds_addr(sr, sg * 32 + 16);
      *(uint4*)(Khi + a0) = kh0;
      *(uint4*)(Khi + a1) = kh1;
      *(uint4*)(Klo + a0) = kl0;
      *(uint4*)(Klo + a1) = kl1;
      #pragma unroll
      for (int i = 0; i < 16; ++i) {
        const int ad = lds_addr(sg * 16 + i, sr * 2);
        *(u16*)(Vthi + ad) = VH.us[i];
        *(u16*)(Vtlo + ad) = VL.us[i];
      }
    }
    __syncthreads();

    // ---- scores: Q · K^T (bf16x3), then exact *1/8 ----
    f32x4 sc[4];
    #pragma unroll
    for (int ct = 0; ct < 4; ++ct) {
      f32x4 s = zero;
      #pragma unroll
      for (int ks = 0; ks < 2; ++ks) {
        const int off = lds_addr(ct * 16 + lrow, ks * 64 + lch * 16);
        bf16x8 kh = *(const bf16x8*)(Khi + off);
        bf16x8 kl = *(const bf16x8*)(Klo + off);
        s = __builtin_amdgcn_mfma_f32_16x16x32_bf16(qh[ks], kh, s, 0, 0, 0);
        s = __builtin_amdgcn_mfma_f32_16x16x32_bf16(qh[ks], kl, s, 0, 0, 0);
        s = __builtin_amdgcn_mfma_f32_16x16x32_bf16(ql[ks], kh, s, 0, 0, 0);
      }
      #pragma unroll
      for (int j = 0; j < 4; ++j) s[j] *= 0.125f;
      sc[ct] = s;
    }

    // ---- causal mask (row q = lch*4+j, col kv = lrow+16ct) ----
    #pragma unroll
    for (int ct = 0; ct < 4; ++ct) {
      const int kj = k0 + lrow + ct * 16;
      #pragma unroll
      for (int j = 0; j < 4; ++j) {
        const int qi = q0 + w * 16 + lch * 4 + j;
        if (kj > qi) sc[ct][j] = -1e30f;
      }
    }

    // ---- online softmax (16-lane row groups) ----
    float tmax[4];
    #pragma unroll
    for (int j = 0; j < 4; ++j)
      tmax[j] = fmaxf(fmaxf(sc[0][j], sc[1][j]), fmaxf(sc[2][j], sc[3][j]));
    #pragma unroll
    for (int off = 1; off < 16; off <<= 1)
      #pragma unroll
      for (int j = 0; j < 4; ++j)
        tmax[j] = fmaxf(tmax[j], __shfl_xor(tmax[j], off, 16));

    float mnew[4], tsum[4];
    #pragma unroll
    for (int j = 0; j < 4; ++j) {
      mnew[j] = fmaxf(m[j], tmax[j]);
      float su = 0.f;
      #pragma unroll
      for (int ct = 0; ct < 4; ++ct) {
        sc[ct][j] = __expf(sc[ct][j] - mnew[j]);
        su += sc[ct][j];
      }
      tsum[j] = su;
    }
    #pragma unroll
    for (int off = 1; off < 16; off <<= 1)
      #pragma unroll
      for (int j = 0; j < 4; ++j) tsum[j] += __shfl_xor(tsum[j], off, 16);
    #pragma unroll
    for (int j = 0; j < 4; ++j) {
      const float co = __expf(m[j] - mnew[j]);
      lsum[j] = lsum[j] * co + tsum[j];
      #pragma unroll
      for (int ct = 0; ct < 4; ++ct) acc[ct][j] *= co;
      m[j] = mnew[j];
    }

    // ---- write P hi/lo (fast cast) ----
    #pragma unroll
    for (int ct = 0; ct < 4; ++ct)
      #pragma unroll
      for (int j = 0; j < 4; ++j) {
        const int ad = lds_addr(w * 16 + lch * 4 + j, (lrow + ct * 16) * 2);
        u16 hu, lu;
        bsplit(sc[ct][j], hu, lu);
        *(u16*)(Phi + ad) = hu;
        *(u16*)(Plo + ad) = lu;
      }
    __syncthreads();               // P visible

    // ---- PV: acc += P · V (bf16x3) ----
    #pragma unroll
    for (int ks = 0; ks < 2; ++ks) {
      const int poff = lds_addr(w * 16 + lrow, ks * 64 + lch * 16);
      bf16x8 ph = *(const bf16x8*)(Phi + poff);
      bf16x8 pl = *(const bf16x8*)(Plo + poff);
      #pragma unroll
      for (int ct = 0; ct < 4; ++ct) {
        const int voff = lds_addr(ct * 16 + lrow, ks * 64 + lch * 16);
        bf16x8 vh = *(const bf16x8*)(Vthi + voff);
        bf16x8 vl = *(const bf16x8*)(Vtlo + voff);
        acc[ct] = __builtin_amdgcn_mfma_f32_16x16x32_bf16(ph, vh, acc[ct], 0, 0, 0);
        acc[ct] = __builtin_amdgcn_mfma_f32_16x16x32_bf16(ph, vl, acc[ct], 0, 0, 0);
        acc[ct] = __builtin_amdgcn_mfma_f32_16x16x32_bf16(pl, vh, acc[ct], 0, 0, 0);
      }
    }
  }

  // ---- epilogue: o hi/lo planes ----
  #pragma unroll
  for (int j = 0; j < 4; ++j) {
    const int s = q0 + w * 16 + lch * 4 + j;
    if (s >= S_LEN) continue;
    const float inv = 1.f / lsum[j];
    #pragma unroll
    for (int ct = 0; ct < 4; ++ct) {
      const size_t idx = ((size_t)b * S_LEN + s) * DIM + hh * HD + lrow + ct * 16;
      u16 hu, lu;
      bsplit(acc[ct][j] * inv, hu, lu);
      o_hi[idx] = hu;
      o_lo[idx] = lu;
    }
  }
}

// ---------------------------------------------------------------------------
extern "C" void kernel_launch(void* const* d_in, const int* in_sizes, int n_in,
                              void* d_out, int out_size, void* d_ws, size_t ws_size,
                              hipStream_t stream) {
  const float* x     = (const float*)d_in[0];
  const int*   pos   = (const int*)d_in[1];
  const float* theta = (const float*)d_in[2];
  const float* ln_w  = (const float*)d_in[3];
  const float* ln_b  = (const float*)d_in[4];
  const float* qkv_w = (const float*)d_in[5];
  const float* qkv_b = (const float*)d_in[6];
  const float* out_w = (const float*)d_in[7];
  const float* out_b = (const float*)d_in[8];
  float* out = (float*)d_out;

  // workspace (bf16 planes; 134.3 MB total — identical to validated layout):
  // h_hi|h_lo [M,1024] each, qkv_hi|qkv_lo [M,3072] each.
  // o planes alias h planes (h dead after QKV GEMM).
  u16* h_hi   = (u16*)d_ws;
  u16* h_lo   = h_hi + (size_t)M_ROWS * DIM;
  u16* qkv_hi = h_lo + (size_t)M_ROWS * DIM;
  u16* qkv_lo = qkv_hi + (size_t)M_ROWS * QKV_DIM;
  u16* o_hi   = h_hi;
  u16* o_lo   = h_lo;

  ln_kernel<<<M_ROWS, 256, 0, stream>>>(x, ln_w, ln_b, h_hi, h_lo);
  gemm_ps<true><<<dim3(65, 24), 256, 0, stream>>>(h_hi, h_lo, qkv_w, qkv_b,
                                                  nullptr, qkv_hi, qkv_lo,
                                                  M_ROWS, QKV_DIM, DIM);
  rope_planes<<<(B_SZ * S_LEN * NH * 32 + 255) / 256, 256, 0, stream>>>(qkv_hi, qkv_lo, pos, theta);
  attn_mfma<<<dim3(17, NH, B_SZ), 256, 0, stream>>>(qkv_hi, qkv_lo, o_hi, o_lo);
  gemm_ps<false><<<dim3(65, 8), 256, 0, stream>>>(o_hi, o_lo, out_w, out_b,
                                                  out, nullptr, nullptr,
                                                  M_ROWS, DIM, DIM);
}